// Round 15
// baseline (130.599 us; speedup 1.0000x reference)
//
#include <hip/hip_runtime.h>
#include <hip/hip_bf16.h>

// GCN: out = GCNConv2( relu( GCNConv1(x) ) )
// Round 14->15: UNFUSE scatter+gemm1. The role-split kernel allocated the UNION
// of both roles' LDS (69KB) -> 2 blocks/CU, 14.9% occupancy, 43.2us (vs ~23us
// serial sum of the standalone kernels). Keep: unscaled h1, epack fma-gather
// agg1, pre-scaled h2, standalone gemm2/agg2 (r14).

constexpr int NN = 50000;
constexpr int NE = 800000;
constexpr int DI = 96;
constexpr int DH = 96;
constexpr int DO = 48;

constexpr int BK_SHIFT = 6;
constexpr int NBK      = (NN + 63) >> 6;     // 782
constexpr int BK_CAP   = 2048;

constexpr int NCHUNK = 256;
constexpr int CH     = (NE + NCHUNK - 1) / NCHUNK;  // 3125

constexpr int G1_ROWS = 64;

typedef unsigned short us4 __attribute__((ext_vector_type(4)));
typedef unsigned short us8 __attribute__((ext_vector_type(8)));

__device__ __forceinline__ float bf2f(unsigned short u) {
    return __uint_as_float(((unsigned int)u) << 16);
}
__device__ __forceinline__ unsigned short f2bf(float f) {
    __hip_bfloat16 b = __float2bfloat16(f);
    return *reinterpret_cast<unsigned short*>(&b);
}

// ---------------- CSR build ----------------

__global__ __launch_bounds__(256) void k_hist(const int* __restrict__ dst,
                                              int* __restrict__ C, int e) {
    __shared__ int hist[NBK];
    for (int i = threadIdx.x; i < NBK; i += 256) hist[i] = 0;
    __syncthreads();
    const int blk = blockIdx.x;
    const int beg = blk * CH, end = min(beg + CH, e);
    for (int i = beg + threadIdx.x; i < end; i += 256)
        atomicAdd(&hist[dst[i] >> BK_SHIFT], 1);
    __syncthreads();
    for (int b = threadIdx.x; b < NBK; b += 256)
        C[b * NCHUNK + blk] = hist[b];
}

__global__ __launch_bounds__(256) void k_rowscan(int* __restrict__ C,
                                                 int* __restrict__ totals,
                                                 int* __restrict__ row_ptr) {
    if (blockIdx.x == 0 && threadIdx.x == 0) row_ptr[NN] = NE;  // sentinel
    const int w    = threadIdx.x >> 6;
    const int lane = threadIdx.x & 63;
    const int r    = blockIdx.x * 4 + w;
    if (r >= NBK) return;
    int* row = C + r * NCHUNK;
    int v[4], s[4];
#pragma unroll
    for (int q = 0; q < 4; ++q) { v[q] = row[q * 64 + lane]; s[q] = v[q]; }
#pragma unroll
    for (int off = 1; off < 64; off <<= 1) {
#pragma unroll
        for (int q = 0; q < 4; ++q) {
            int y = __shfl_up(s[q], off);
            if (lane >= off) s[q] += y;
        }
    }
    int c0 = __shfl(s[0], 63);
    int c1 = __shfl(s[1], 63);
    int c2 = __shfl(s[2], 63);
    s[1] += c0;
    s[2] += c0 + c1;
    s[3] += c0 + c1 + c2;
#pragma unroll
    for (int q = 0; q < 4; ++q) row[q * 64 + lane] = s[q] - v[q];
    if (lane == 63) totals[r] = s[3];
}

// standalone scatter: in-LDS scan of totals -> bases; LDS cursors; no global atomics
__global__ __launch_bounds__(256) void k_scatter(const int* __restrict__ src,
                                                 const int* __restrict__ dst,
                                                 const int* __restrict__ C,
                                                 const int* __restrict__ totals,
                                                 int* __restrict__ bk_ptr,
                                                 unsigned* __restrict__ ebuf, int e) {
    __shared__ int bkL[NBK + 1];
    __shared__ int part[256];
    __shared__ int cur[NBK];
    const int t = threadIdx.x;

    int v[4];
    int s = 0;
    const int base = t * 4;
#pragma unroll
    for (int i = 0; i < 4; ++i) {
        int idx = base + i;
        v[i] = (idx < NBK) ? totals[idx] : 0;
        s += v[i];
    }
    part[t] = s;
    __syncthreads();
#pragma unroll
    for (int off = 1; off < 256; off <<= 1) {
        int x = part[t];
        int a = (t >= off) ? part[t - off] : 0;
        __syncthreads();
        part[t] = x + a;
        __syncthreads();
    }
    int run = part[t] - s;
#pragma unroll
    for (int i = 0; i < 4; ++i) {
        int idx = base + i;
        if (idx <= NBK) bkL[idx] = run;
        run += v[i];
    }
    __syncthreads();

    const int blk = blockIdx.x;
    for (int b = t; b < NBK; b += 256) cur[b] = bkL[b] + C[b * NCHUNK + blk];
    if (blk == 0)
        for (int i = t; i <= NBK; i += 256) bk_ptr[i] = bkL[i];
    __syncthreads();

    const int beg = blk * CH, end = min(beg + CH, e);
    for (int i = beg + t; i < end; i += 256) {
        int d = dst[i];
        int b = d >> BK_SHIFT;
        int pos = atomicAdd(&cur[b], 1);   // LDS atomic
        ebuf[pos] = ((unsigned)(d & 63) << 16) | (unsigned)src[i];
    }
}

// standalone GEMM 1: h1[n][96] = bf16(x @ W1), UNSCALED (no dinv dependency)
__global__ __launch_bounds__(256) void k_gemm1(const float* __restrict__ X,
                                               const float* __restrict__ W,
                                               unsigned short* __restrict__ H, int n) {
    constexpr int P = 97;
    __shared__ float ws[DI * DH];          // 36.9 KB
    __shared__ float xs[G1_ROWS * P];      // 24.8 KB (aliased as hout)
    unsigned short* hout = reinterpret_cast<unsigned short*>(xs);

    const int t    = threadIdx.x;
    const int row0 = blockIdx.x * G1_ROWS;

    for (int i = t; i < DI * DH; i += 256) ws[i] = W[i];
    {
        const float4* Xv = reinterpret_cast<const float4*>(X + (size_t)row0 * DI);
        const int nv   = G1_ROWS * DI / 4;              // 1536
        const int maxv = ((n - row0) * DI) / 4;
        for (int i = t; i < nv; i += 256) {
            float4 v = (i < maxv) ? Xv[i] : float4{0.f, 0.f, 0.f, 0.f};
            int r = i / 24, c = (i % 24) * 4;
            xs[r * P + c + 0] = v.x;
            xs[r * P + c + 1] = v.y;
            xs[r * P + c + 2] = v.z;
            xs[r * P + c + 3] = v.w;
        }
    }
    __syncthreads();

    const int cg = t & 15, rg = t >> 4;
    float acc[4][6] = {};
#pragma unroll 2
    for (int k = 0; k < DI; ++k) {
        float xv[4];
#pragma unroll
        for (int i = 0; i < 4; ++i) xv[i] = xs[(rg * 4 + i) * P + k];
#pragma unroll
        for (int j = 0; j < 6; ++j) {
            float wv = ws[k * DH + cg * 6 + j];
#pragma unroll
            for (int i = 0; i < 4; ++i) acc[i][j] += xv[i] * wv;
        }
    }
    __syncthreads();

#pragma unroll
    for (int i = 0; i < 4; ++i) {
#pragma unroll
        for (int j = 0; j < 6; ++j)
            hout[(rg * 4 + i) * 96 + cg * 6 + j] = f2bf(acc[i][j]);
    }
    __syncthreads();

    {
        const us8* ho8 = reinterpret_cast<const us8*>(hout);
        us8* H8 = reinterpret_cast<us8*>(H + (size_t)row0 * DH);
        const int nv   = G1_ROWS * DH / 8;              // 768
        const int maxv = ((n - row0) * DH) / 8;
        for (int i = t; i < nv && i < maxv; i += 256) H8[i] = ho8[i];
    }
}

__global__ __launch_bounds__(256) void k_bsort(const unsigned* __restrict__ ebuf,
                                               const int* __restrict__ bk_ptr,
                                               int* __restrict__ row_ptr,
                                               float* __restrict__ dinv,
                                               unsigned short* __restrict__ src16, int n) {
    __shared__ unsigned eL[BK_CAP];
    __shared__ unsigned short outL[BK_CAP];
    __shared__ int curL[64];
    __shared__ int baseL[64];

    const int b   = blockIdx.x;
    const int beg = bk_ptr[b];
    const int m   = bk_ptr[b + 1] - beg;
    const int t   = threadIdx.x;

    if (t < 64) curL[t] = 0;
    __syncthreads();

    for (int i = t; i < m; i += 256) {
        unsigned v = ebuf[beg + i];
        eL[i] = v;
        atomicAdd(&curL[v >> 16], 1);
    }
    __syncthreads();

    if (t < 64) {
        int c = curL[t];
        int x = c;
#pragma unroll
        for (int off = 1; off < 64; off <<= 1) {
            int y = __shfl_up(x, off);
            if (t >= off) x += y;
        }
        int excl = x - c;
        baseL[t] = excl;
        int d0 = (b << BK_SHIFT) + t;
        if (d0 < n) {
            row_ptr[d0] = beg + excl;
            dinv[d0]    = rsqrtf((float)(c + 1));   // +1 self-loop
        }
    }
    __syncthreads();
    if (t < 64) curL[t] = baseL[t];
    __syncthreads();

    for (int i = t; i < m; i += 256) {
        unsigned v = eL[i];
        int p = atomicAdd(&curL[v >> 16], 1);
        outL[p] = (unsigned short)(v & 0xFFFFu);
    }
    __syncthreads();
    for (int i = t; i < m; i += 256) src16[beg + i] = outL[i];
}

// pack edge list: epack[i] = (bf16(dinv[src]) << 16) | src
__global__ __launch_bounds__(256) void k_pack(const unsigned short* __restrict__ src16,
                                              const float* __restrict__ dinv,
                                              unsigned* __restrict__ epack, int e) {
    int i2 = (blockIdx.x * 256 + threadIdx.x) * 2;
    if (i2 + 1 < e) {
        unsigned pairv = *reinterpret_cast<const unsigned*>(src16 + i2);
        unsigned s0 = pairv & 0xFFFFu;
        unsigned s1 = pairv >> 16;
        unsigned w0 = f2bf(dinv[s0]);
        unsigned w1 = f2bf(dinv[s1]);
        uint2 o;
        o.x = (w0 << 16) | s0;
        o.y = (w1 << 16) | s1;
        *reinterpret_cast<uint2*>(epack + i2) = o;
    } else if (i2 < e) {
        unsigned s0 = src16[i2];
        epack[i2] = ((unsigned)f2bf(dinv[s0]) << 16) | s0;
    }
}

// ---------------- layer-1 aggregation ----------------
// a1[d] = bf16( relu( dinv_d*( dinv_d*h1[d] + sum_s w_s*h1[s] ) + b1 ) )

__global__ __launch_bounds__(256) void k_agg1(const unsigned short* __restrict__ h1,
                                              const float* __restrict__ dinv,
                                              const int* __restrict__ row_ptr,
                                              const unsigned* __restrict__ epack,
                                              const float* __restrict__ b1,
                                              unsigned short* __restrict__ a1, int n) {
    constexpr int G = 12;
    int t = blockIdx.x * blockDim.x + threadIdx.x;
    if (t >= n * G) return;
    const int node = t / G;
    const int g    = t % G;

    const us8* h8 = reinterpret_cast<const us8*>(h1);
    const float di = dinv[node];

    float accA[8], accB[8];
    {
        us8 hv = h8[(size_t)node * G + g];   // self term (unscaled h1)
#pragma unroll
        for (int j = 0; j < 8; ++j) { accA[j] = di * bf2f(hv[j]); accB[j] = 0.f; }
    }

    const int beg = row_ptr[node];
    const int end = row_ptr[node + 1];
    int k = beg;
    int kA = min((beg + 7) & ~7, end);
    for (; k < kA; ++k) {
        unsigned ev = epack[k];
        float w = bf2f((unsigned short)(ev >> 16));
        us8 vv = h8[(size_t)(ev & 0xFFFFu) * G + g];
#pragma unroll
        for (int j = 0; j < 8; ++j) accA[j] += w * bf2f(vv[j]);
    }
    for (; k + 8 <= end; k += 8) {
        const uint4* ev4 = reinterpret_cast<const uint4*>(epack + k);
        uint4 e0 = ev4[0], e1 = ev4[1];
        us8 v0 = h8[(size_t)(e0.x & 0xFFFFu) * G + g];
        us8 v1 = h8[(size_t)(e0.y & 0xFFFFu) * G + g];
        us8 v2 = h8[(size_t)(e0.z & 0xFFFFu) * G + g];
        us8 v3 = h8[(size_t)(e0.w & 0xFFFFu) * G + g];
        us8 v4 = h8[(size_t)(e1.x & 0xFFFFu) * G + g];
        us8 v5 = h8[(size_t)(e1.y & 0xFFFFu) * G + g];
        us8 v6 = h8[(size_t)(e1.z & 0xFFFFu) * G + g];
        us8 v7 = h8[(size_t)(e1.w & 0xFFFFu) * G + g];
        float w0 = bf2f((unsigned short)(e0.x >> 16));
        float w1 = bf2f((unsigned short)(e0.y >> 16));
        float w2 = bf2f((unsigned short)(e0.z >> 16));
        float w3 = bf2f((unsigned short)(e0.w >> 16));
        float w4 = bf2f((unsigned short)(e1.x >> 16));
        float w5 = bf2f((unsigned short)(e1.y >> 16));
        float w6 = bf2f((unsigned short)(e1.z >> 16));
        float w7 = bf2f((unsigned short)(e1.w >> 16));
#pragma unroll
        for (int j = 0; j < 8; ++j) {
            accA[j] += w0 * bf2f(v0[j]) + w1 * bf2f(v1[j])
                     + w4 * bf2f(v4[j]) + w5 * bf2f(v5[j]);
            accB[j] += w2 * bf2f(v2[j]) + w3 * bf2f(v3[j])
                     + w6 * bf2f(v6[j]) + w7 * bf2f(v7[j]);
        }
    }
    for (; k < end; ++k) {
        unsigned ev = epack[k];
        float w = bf2f((unsigned short)(ev >> 16));
        us8 vv = h8[(size_t)(ev & 0xFFFFu) * G + g];
#pragma unroll
        for (int j = 0; j < 8; ++j) accB[j] += w * bf2f(vv[j]);
    }

    us8 o;
#pragma unroll
    for (int j = 0; j < 8; ++j) {
        float r = di * (accA[j] + accB[j]) + b1[g * 8 + j];
        o[j] = f2bf(fmaxf(r, 0.f));           // relu
    }
    reinterpret_cast<us8*>(a1)[(size_t)node * G + g] = o;
}

// ---------------- GEMM 2: h2[n][48] = bf16( dinv * (a1 bf16 @ W2) ) ----------------

__global__ __launch_bounds__(256) void k_gemm2(const unsigned short* __restrict__ A,
                                               const float* __restrict__ W,
                                               const float* __restrict__ dinv,
                                               unsigned short* __restrict__ H, int n) {
    constexpr int ROWS = 64, P = 98;
    __shared__ float ws[DH * DO];           // 18.4 KB
    __shared__ unsigned short xs[ROWS * P]; // 12.5 KB (aliased as hout)

    const int tid  = threadIdx.x;
    const int row0 = blockIdx.x * ROWS;

    for (int i = tid; i < DH * DO; i += 256) ws[i] = W[i];
    {
        const us8* Av = reinterpret_cast<const us8*>(A + (size_t)row0 * DH);
        const int nv   = ROWS * DH / 8;                 // 768
        const int maxv = ((n - row0) * DH) / 8;
        for (int i = tid; i < nv; i += 256) {
            us8 v = (i < maxv) ? Av[i] : (us8)(0);
            int r = i / 12, c = (i % 12) * 8;
#pragma unroll
            for (int jj = 0; jj < 8; ++jj) xs[r * P + c + jj] = v[jj];
        }
    }
    __syncthreads();

    const int cg = tid & 15, rg = tid >> 4;
    float acc[4][3] = {};
#pragma unroll 2
    for (int k = 0; k < DH; ++k) {
        float xv[4];
#pragma unroll
        for (int i = 0; i < 4; ++i) xv[i] = bf2f(xs[(rg * 4 + i) * P + k]);
#pragma unroll
        for (int j = 0; j < 3; ++j) {
            float wv = ws[k * DO + cg * 3 + j];
#pragma unroll
            for (int i = 0; i < 4; ++i) acc[i][j] += xv[i] * wv;
        }
    }
    __syncthreads();

    unsigned short* hout = xs;
#pragma unroll
    for (int i = 0; i < 4; ++i) {
        int row = row0 + rg * 4 + i;
        float dv = (row < n) ? dinv[row] : 0.f;
#pragma unroll
        for (int j = 0; j < 3; ++j)
            hout[(rg * 4 + i) * 48 + cg * 3 + j] = f2bf(acc[i][j] * dv);
    }
    __syncthreads();

    {
        const us8* ho8 = reinterpret_cast<const us8*>(hout);
        us8* H8 = reinterpret_cast<us8*>(H + (size_t)row0 * DO);
        const int nv   = ROWS * DO / 8;                 // 384
        const int maxv = ((n - row0) * DO) / 8;
        for (int i = tid; i < nv && i < maxv; i += 256) H8[i] = ho8[i];
    }
}

// ---------------- layer-2 aggregation: dense, pre-scaled h2 ----------------

__global__ __launch_bounds__(256) void k_agg2(const unsigned short* __restrict__ h,
                                              const float* __restrict__ dinv,
                                              const int* __restrict__ row_ptr,
                                              const unsigned short* __restrict__ src16,
                                              const float* __restrict__ bias,
                                              float* __restrict__ outp, int n) {
    constexpr int G = 6;
    int t = blockIdx.x * blockDim.x + threadIdx.x;
    if (t >= n * G) return;
    const int node = t / G;
    const int g    = t % G;

    const us8* h8 = reinterpret_cast<const us8*>(h);

    float accA[8], accB[8];
    {
        us8 hv = h8[(size_t)node * G + g];
#pragma unroll
        for (int j = 0; j < 8; ++j) { accA[j] = bf2f(hv[j]); accB[j] = 0.f; }
    }

    const int beg = row_ptr[node];
    const int end = row_ptr[node + 1];
    int k = beg;
    int kA = min((beg + 7) & ~7, end);
    for (; k < kA; ++k) {
        us8 vv = h8[(size_t)src16[k] * G + g];
#pragma unroll
        for (int j = 0; j < 8; ++j) accA[j] += bf2f(vv[j]);
    }
    for (; k + 8 <= end; k += 8) {
        us8 si = *reinterpret_cast<const us8*>(src16 + k);
        us8 v0 = h8[(size_t)si[0] * G + g];
        us8 v1 = h8[(size_t)si[1] * G + g];
        us8 v2 = h8[(size_t)si[2] * G + g];
        us8 v3 = h8[(size_t)si[3] * G + g];
        us8 v4 = h8[(size_t)si[4] * G + g];
        us8 v5 = h8[(size_t)si[5] * G + g];
        us8 v6 = h8[(size_t)si[6] * G + g];
        us8 v7 = h8[(size_t)si[7] * G + g];
#pragma unroll
        for (int j = 0; j < 8; ++j) {
            accA[j] += (bf2f(v0[j]) + bf2f(v1[j])) + (bf2f(v4[j]) + bf2f(v5[j]));
            accB[j] += (bf2f(v2[j]) + bf2f(v3[j])) + (bf2f(v6[j]) + bf2f(v7[j]));
        }
    }
    for (; k < end; ++k) {
        us8 vv = h8[(size_t)src16[k] * G + g];
#pragma unroll
        for (int j = 0; j < 8; ++j) accB[j] += bf2f(vv[j]);
    }

    const float di = dinv[node];
    const float4* b4 = reinterpret_cast<const float4*>(bias);
    float4 b0 = b4[g * 2], b1 = b4[g * 2 + 1];
    float r[8];
#pragma unroll
    for (int j = 0; j < 8; ++j) r[j] = di * (accA[j] + accB[j]);
    r[0] += b0.x; r[1] += b0.y; r[2] += b0.z; r[3] += b0.w;
    r[4] += b1.x; r[5] += b1.y; r[6] += b1.z; r[7] += b1.w;
    float4* o4 = reinterpret_cast<float4*>(outp + (size_t)node * DO + g * 8);
    o4[0] = float4{r[0], r[1], r[2], r[3]};
    o4[1] = float4{r[4], r[5], r[6], r[7]};
}

// ---------------- launch ----------------

extern "C" void kernel_launch(void* const* d_in, const int* in_sizes, int n_in,
                              void* d_out, int out_size, void* d_ws, size_t ws_size,
                              hipStream_t stream) {
    const float* x   = (const float*)d_in[0];
    const int*   ei  = (const int*)d_in[1];   // [2][NE] int32
    const float* W1  = (const float*)d_in[2];
    const float* b1  = (const float*)d_in[3];
    const float* W2  = (const float*)d_in[4];
    const float* b2  = (const float*)d_in[5];
    float*       out = (float*)d_out;

    const int* srcv = ei;
    const int* dstv = ei + NE;

    // workspace layout (16B-aligned blocks)
    char* p = (char*)d_ws;
    float*          dinv  = (float*)p;           p += (size_t)NN * 4;
    unsigned short* h1    = (unsigned short*)p;  p += (size_t)NN * DH * 2;   // unscaled
    unsigned short* a1    = (unsigned short*)p;  p += (size_t)NN * DH * 2;
    unsigned short* h2    = (unsigned short*)p;  p += (size_t)NN * DO * 2;   // pre-scaled
    int*      row_ptr     = (int*)p;             p += (size_t)(NN + 16) * 4;
    unsigned short* src16 = (unsigned short*)p;  p += (size_t)NE * 2;
    unsigned* epack       = (unsigned*)p;        p += (size_t)NE * 4;
    unsigned* ebuf        = (unsigned*)p;        p += (size_t)NE * 4;
    int*      Cm          = (int*)p;             p += (size_t)NBK * NCHUNK * 4;
    int*      totals      = (int*)p;             p += (size_t)NBK * 4;
    int*      bk_ptr      = (int*)p;             p += (size_t)(NBK + 1) * 4;

    const int B = 256;

    k_hist<<<NCHUNK, B, 0, stream>>>(dstv, Cm, NE);
    k_rowscan<<<(NBK + 3) / 4, B, 0, stream>>>(Cm, totals, row_ptr);
    k_scatter<<<NCHUNK, B, 0, stream>>>(srcv, dstv, Cm, totals, bk_ptr, ebuf, NE);
    k_gemm1<<<(NN + G1_ROWS - 1) / G1_ROWS, B, 0, stream>>>(x, W1, h1, NN);
    k_bsort<<<NBK, B, 0, stream>>>(ebuf, bk_ptr, row_ptr, dinv, src16, NN);
    k_pack<<<(NE / 2 + B - 1) / B, B, 0, stream>>>(src16, dinv, epack, NE);

    {
        int total = NN * 12;
        k_agg1<<<(total + B - 1) / B, B, 0, stream>>>(
            h1, dinv, row_ptr, epack, b1, a1, NN);
    }
    k_gemm2<<<(NN + 63) / 64, B, 0, stream>>>(a1, W2, dinv, h2, NN);
    {
        int total = NN * 6;
        k_agg2<<<(total + B - 1) / B, B, 0, stream>>>(
            h2, dinv, row_ptr, src16, b2, out, NN);
    }
}

// Round 16
// 116.371 us; speedup vs baseline: 1.1223x; 1.1223x over previous
//
#include <hip/hip_runtime.h>
#include <hip/hip_bf16.h>

// GCN: out = GCNConv2( relu( GCNConv1(x) ) )
// Round 15->16: r13 structure (best, 120.8us) + occupancy fixes on the two
// fused kernels, arithmetic unchanged:
//  - scatter_gemm1: gemm role 32 rows/block; roles ALIAS one 49.3KB smem block
//    (r13 summed to 69KB -> 2 blocks/CU, 14.9% occ). Now 3 blocks/CU.
//  - agg1_gemm2: 512-thr blocks, 42 nodes (27.2KB LDS) -> 4 blocks/CU = 2048
//    resident threads (was 2x768=1536, thread-capped).
// Record: fused > unfused here (r14/r15 proved both splits regress).

constexpr int NN = 50000;
constexpr int NE = 800000;
constexpr int DI = 96;
constexpr int DH = 96;
constexpr int DO = 48;

constexpr int BK_SHIFT = 6;
constexpr int NBK      = (NN + 63) >> 6;     // 782
constexpr int BK_CAP   = 2048;

constexpr int NCHUNK = 256;
constexpr int CH     = (NE + NCHUNK - 1) / NCHUNK;  // 3125

constexpr int G1_ROWS = 32;
constexpr int NG1     = (NN + G1_ROWS - 1) / G1_ROWS;  // 1563

constexpr int A2_NODES = 42;                 // nodes per agg1_gemm2 block
constexpr int NB2      = (NN + A2_NODES - 1) / A2_NODES;  // 1191

typedef unsigned short us4 __attribute__((ext_vector_type(4)));
typedef unsigned short us8 __attribute__((ext_vector_type(8)));

__device__ __forceinline__ float bf2f(unsigned short u) {
    return __uint_as_float(((unsigned int)u) << 16);
}
__device__ __forceinline__ unsigned short f2bf(float f) {
    __hip_bfloat16 b = __float2bfloat16(f);
    return *reinterpret_cast<unsigned short*>(&b);
}

// ---------------- CSR build ----------------

__global__ __launch_bounds__(256) void k_hist(const int* __restrict__ dst,
                                              int* __restrict__ C, int e) {
    __shared__ int hist[NBK];
    for (int i = threadIdx.x; i < NBK; i += 256) hist[i] = 0;
    __syncthreads();
    const int blk = blockIdx.x;
    const int beg = blk * CH, end = min(beg + CH, e);
    for (int i = beg + threadIdx.x; i < end; i += 256)
        atomicAdd(&hist[dst[i] >> BK_SHIFT], 1);
    __syncthreads();
    for (int b = threadIdx.x; b < NBK; b += 256)
        C[b * NCHUNK + blk] = hist[b];
}

__global__ __launch_bounds__(256) void k_rowscan(int* __restrict__ C,
                                                 int* __restrict__ totals,
                                                 int* __restrict__ row_ptr) {
    if (blockIdx.x == 0 && threadIdx.x == 0) row_ptr[NN] = NE;  // sentinel
    const int w    = threadIdx.x >> 6;
    const int lane = threadIdx.x & 63;
    const int r    = blockIdx.x * 4 + w;
    if (r >= NBK) return;
    int* row = C + r * NCHUNK;
    int v[4], s[4];
#pragma unroll
    for (int q = 0; q < 4; ++q) { v[q] = row[q * 64 + lane]; s[q] = v[q]; }
#pragma unroll
    for (int off = 1; off < 64; off <<= 1) {
#pragma unroll
        for (int q = 0; q < 4; ++q) {
            int y = __shfl_up(s[q], off);
            if (lane >= off) s[q] += y;
        }
    }
    int c0 = __shfl(s[0], 63);
    int c1 = __shfl(s[1], 63);
    int c2 = __shfl(s[2], 63);
    s[1] += c0;
    s[2] += c0 + c1;
    s[3] += c0 + c1 + c2;
#pragma unroll
    for (int q = 0; q < 4; ++q) row[q * 64 + lane] = s[q] - v[q];
    if (lane == 63) totals[r] = s[3];
}

// fused: blocks [0,NCHUNK) scatter; blocks [NCHUNK,..) gemm1 (h1 = bf16(x@W1),
// unscaled). Roles ALIAS one smem block: gemm needs 49280B, scatter 7284B.
__global__ __launch_bounds__(256) void k_scatter_gemm1(
        const int* __restrict__ src, const int* __restrict__ dst,
        const int* __restrict__ C, const int* __restrict__ totals,
        int* __restrict__ bk_ptr, unsigned* __restrict__ ebuf, int e,
        const float* __restrict__ X, const float* __restrict__ W,
        unsigned short* __restrict__ H, int n) {
    constexpr int P = 97;
    __shared__ __align__(16) char smem[(DI * DH + G1_ROWS * P) * 4];  // 49280 B

    const int t = threadIdx.x;

    if (blockIdx.x < NCHUNK) {
        // ---- scatter role (aliases smem) ----
        int* bkL  = reinterpret_cast<int*>(smem);           // NBK+1
        int* part = bkL + (NBK + 1);                        // 256
        int* cur  = part + 256;                             // NBK

        int v[4];
        int s = 0;
        const int base = t * 4;
#pragma unroll
        for (int i = 0; i < 4; ++i) {
            int idx = base + i;
            v[i] = (idx < NBK) ? totals[idx] : 0;
            s += v[i];
        }
        part[t] = s;
        __syncthreads();
#pragma unroll
        for (int off = 1; off < 256; off <<= 1) {
            int x = part[t];
            int a = (t >= off) ? part[t - off] : 0;
            __syncthreads();
            part[t] = x + a;
            __syncthreads();
        }
        int run = part[t] - s;
#pragma unroll
        for (int i = 0; i < 4; ++i) {
            int idx = base + i;
            if (idx <= NBK) bkL[idx] = run;
            run += v[i];
        }
        __syncthreads();

        const int blk = blockIdx.x;
        for (int b = t; b < NBK; b += 256) cur[b] = bkL[b] + C[b * NCHUNK + blk];
        if (blk == 0)
            for (int i = t; i <= NBK; i += 256) bk_ptr[i] = bkL[i];
        __syncthreads();

        const int beg = blk * CH, end = min(beg + CH, e);
        for (int i = beg + t; i < end; i += 256) {
            int d = dst[i];
            int b = d >> BK_SHIFT;
            int pos = atomicAdd(&cur[b], 1);   // LDS atomic
            ebuf[pos] = ((unsigned)(d & 63) << 16) | (unsigned)src[i];
        }
    } else {
        // ---- gemm1 role: 32 rows/block ----
        float* ws = reinterpret_cast<float*>(smem);         // DI*DH
        float* xs = ws + DI * DH;                           // G1_ROWS*P
        unsigned short* hout = reinterpret_cast<unsigned short*>(xs);

        const int row0 = (blockIdx.x - NCHUNK) * G1_ROWS;

        for (int i = t; i < DI * DH; i += 256) ws[i] = W[i];
        {
            const float4* Xv = reinterpret_cast<const float4*>(X + (size_t)row0 * DI);
            const int nv   = G1_ROWS * DI / 4;              // 768
            const int maxv = ((n - row0) * DI) / 4;
            for (int i = t; i < nv; i += 256) {
                float4 v = (i < maxv) ? Xv[i] : float4{0.f, 0.f, 0.f, 0.f};
                int r = i / 24, c = (i % 24) * 4;
                xs[r * P + c + 0] = v.x;
                xs[r * P + c + 1] = v.y;
                xs[r * P + c + 2] = v.z;
                xs[r * P + c + 3] = v.w;
            }
        }
        __syncthreads();

        const int cg = t & 15, rg = t >> 4;
        float acc[2][6] = {};
#pragma unroll 2
        for (int k = 0; k < DI; ++k) {
            float xv[2];
#pragma unroll
            for (int i = 0; i < 2; ++i) xv[i] = xs[(rg * 2 + i) * P + k];
#pragma unroll
            for (int j = 0; j < 6; ++j) {
                float wv = ws[k * DH + cg * 6 + j];
#pragma unroll
                for (int i = 0; i < 2; ++i) acc[i][j] += xv[i] * wv;
            }
        }
        __syncthreads();   // xs reads done before aliasing

#pragma unroll
        for (int i = 0; i < 2; ++i) {
#pragma unroll
            for (int j = 0; j < 6; ++j)
                hout[(rg * 2 + i) * 96 + cg * 6 + j] = f2bf(acc[i][j]);
        }
        __syncthreads();

        {
            const us8* ho8 = reinterpret_cast<const us8*>(hout);
            us8* H8 = reinterpret_cast<us8*>(H + (size_t)row0 * DH);
            const int nv   = G1_ROWS * DH / 8;              // 384
            const int maxv = ((n - row0) * DH) / 8;
            for (int i = t; i < nv && i < maxv; i += 256) H8[i] = ho8[i];
        }
    }
}

__global__ __launch_bounds__(256) void k_bsort(const unsigned* __restrict__ ebuf,
                                               const int* __restrict__ bk_ptr,
                                               int* __restrict__ row_ptr,
                                               float* __restrict__ dinv,
                                               unsigned short* __restrict__ src16, int n) {
    __shared__ unsigned eL[BK_CAP];
    __shared__ unsigned short outL[BK_CAP];
    __shared__ int curL[64];
    __shared__ int baseL[64];

    const int b   = blockIdx.x;
    const int beg = bk_ptr[b];
    const int m   = bk_ptr[b + 1] - beg;
    const int t   = threadIdx.x;

    if (t < 64) curL[t] = 0;
    __syncthreads();

    for (int i = t; i < m; i += 256) {
        unsigned v = ebuf[beg + i];
        eL[i] = v;
        atomicAdd(&curL[v >> 16], 1);
    }
    __syncthreads();

    if (t < 64) {
        int c = curL[t];
        int x = c;
#pragma unroll
        for (int off = 1; off < 64; off <<= 1) {
            int y = __shfl_up(x, off);
            if (t >= off) x += y;
        }
        int excl = x - c;
        baseL[t] = excl;
        int d0 = (b << BK_SHIFT) + t;
        if (d0 < n) {
            row_ptr[d0] = beg + excl;
            dinv[d0]    = rsqrtf((float)(c + 1));   // +1 self-loop
        }
    }
    __syncthreads();
    if (t < 64) curL[t] = baseL[t];
    __syncthreads();

    for (int i = t; i < m; i += 256) {
        unsigned v = eL[i];
        int p = atomicAdd(&curL[v >> 16], 1);
        outL[p] = (unsigned short)(v & 0xFFFFu);
    }
    __syncthreads();
    for (int i = t; i < m; i += 256) src16[beg + i] = outL[i];
}

// pack edge list: epack[i] = (bf16(dinv[src]) << 16) | src
__global__ __launch_bounds__(256) void k_pack(const unsigned short* __restrict__ src16,
                                              const float* __restrict__ dinv,
                                              unsigned* __restrict__ epack, int e) {
    int i2 = (blockIdx.x * 256 + threadIdx.x) * 2;
    if (i2 + 1 < e) {
        unsigned pairv = *reinterpret_cast<const unsigned*>(src16 + i2);
        unsigned s0 = pairv & 0xFFFFu;
        unsigned s1 = pairv >> 16;
        unsigned w0 = f2bf(dinv[s0]);
        unsigned w1 = f2bf(dinv[s1]);
        uint2 o;
        o.x = (w0 << 16) | s0;
        o.y = (w1 << 16) | s1;
        *reinterpret_cast<uint2*>(epack + i2) = o;
    } else if (i2 < e) {
        unsigned s0 = src16[i2];
        epack[i2] = ((unsigned)f2bf(dinv[s0]) << 16) | s0;
    }
}

// ---------------- fused agg1 + gemm2 ----------------
// 512 threads, 42 nodes/block (504 active). Phase A: agg over epack -> LDS a1
// tile (+bias, relu). Phase B: h2 = bf16(dinv*(a1_tile @ W2)).

__global__ __launch_bounds__(512) void k_agg1_gemm2(
        const unsigned short* __restrict__ h1,
        const float* __restrict__ dinv,
        const int* __restrict__ row_ptr,
        const unsigned* __restrict__ epack,
        const float* __restrict__ b1,
        const float* __restrict__ W2,
        unsigned short* __restrict__ h2, int n) {
    constexpr int P2 = 104;
    __shared__ unsigned short a1t[A2_NODES * P2];  // 8736 B
    __shared__ float ws[DH * DO];                  // 18432 B

    const int t = threadIdx.x;
    for (int i = t; i < DH * DO; i += 512) ws[i] = W2[i];

    const int rloc = t / 12;              // 0..42 (42 only for idle tail)
    const int g    = t % 12;
    const bool active = (t < A2_NODES * 12);
    const int node = blockIdx.x * A2_NODES + rloc;

    if (active && node < n) {
        const us8* h8 = reinterpret_cast<const us8*>(h1);
        const float di = dinv[node];

        float accA[8], accB[8];
        {
            us8 hv = h8[(size_t)node * 12 + g];   // self term (unscaled h1)
#pragma unroll
            for (int j = 0; j < 8; ++j) { accA[j] = di * bf2f(hv[j]); accB[j] = 0.f; }
        }

        const int beg = row_ptr[node];
        const int end = row_ptr[node + 1];
        int k = beg;
        int kA = min((beg + 7) & ~7, end);
        for (; k < kA; ++k) {
            unsigned ev = epack[k];
            float w = bf2f((unsigned short)(ev >> 16));
            us8 vv = h8[(size_t)(ev & 0xFFFFu) * 12 + g];
#pragma unroll
            for (int j = 0; j < 8; ++j) accA[j] += w * bf2f(vv[j]);
        }
        for (; k + 8 <= end; k += 8) {
            const uint4* ev4 = reinterpret_cast<const uint4*>(epack + k);
            uint4 e0 = ev4[0], e1 = ev4[1];
            us8 v0 = h8[(size_t)(e0.x & 0xFFFFu) * 12 + g];
            us8 v1 = h8[(size_t)(e0.y & 0xFFFFu) * 12 + g];
            us8 v2 = h8[(size_t)(e0.z & 0xFFFFu) * 12 + g];
            us8 v3 = h8[(size_t)(e0.w & 0xFFFFu) * 12 + g];
            us8 v4 = h8[(size_t)(e1.x & 0xFFFFu) * 12 + g];
            us8 v5 = h8[(size_t)(e1.y & 0xFFFFu) * 12 + g];
            us8 v6 = h8[(size_t)(e1.z & 0xFFFFu) * 12 + g];
            us8 v7 = h8[(size_t)(e1.w & 0xFFFFu) * 12 + g];
            float w0 = bf2f((unsigned short)(e0.x >> 16));
            float w1 = bf2f((unsigned short)(e0.y >> 16));
            float w2 = bf2f((unsigned short)(e0.z >> 16));
            float w3 = bf2f((unsigned short)(e0.w >> 16));
            float w4 = bf2f((unsigned short)(e1.x >> 16));
            float w5 = bf2f((unsigned short)(e1.y >> 16));
            float w6 = bf2f((unsigned short)(e1.z >> 16));
            float w7 = bf2f((unsigned short)(e1.w >> 16));
#pragma unroll
            for (int j = 0; j < 8; ++j) {
                accA[j] += w0 * bf2f(v0[j]) + w1 * bf2f(v1[j])
                         + w4 * bf2f(v4[j]) + w5 * bf2f(v5[j]);
                accB[j] += w2 * bf2f(v2[j]) + w3 * bf2f(v3[j])
                         + w6 * bf2f(v6[j]) + w7 * bf2f(v7[j]);
            }
        }
        for (; k < end; ++k) {
            unsigned ev = epack[k];
            float w = bf2f((unsigned short)(ev >> 16));
            us8 vv = h8[(size_t)(ev & 0xFFFFu) * 12 + g];
#pragma unroll
            for (int j = 0; j < 8; ++j) accB[j] += w * bf2f(vv[j]);
        }

        us8 o;
#pragma unroll
        for (int j = 0; j < 8; ++j) {
            float r = di * (accA[j] + accB[j]) + b1[g * 8 + j];
            o[j] = f2bf(fmaxf(r, 0.f));           // relu
        }
        *reinterpret_cast<us8*>(a1t + rloc * P2 + g * 8) = o;
    }
    __syncthreads();

    // ---- phase B: gemm2 on the LDS tile ----
    if (active) {
        const int c0 = g * 4;                 // 0..44
        float acc[4] = {};
#pragma unroll 2
        for (int k = 0; k < DH; ++k) {
            float xv = bf2f(a1t[rloc * P2 + k]);
#pragma unroll
            for (int j = 0; j < 4; ++j) acc[j] += xv * ws[k * DO + c0 + j];
        }
        if (node < n) {
            float dv = dinv[node];
            us4 o;
#pragma unroll
            for (int j = 0; j < 4; ++j) o[j] = f2bf(acc[j] * dv);
            *reinterpret_cast<us4*>(h2 + (size_t)node * DO + c0) = o;
        }
    }
}

// ---------------- layer-2 aggregation: dense, pre-scaled h2 ----------------

__global__ __launch_bounds__(256) void k_agg2(const unsigned short* __restrict__ h,
                                              const float* __restrict__ dinv,
                                              const int* __restrict__ row_ptr,
                                              const unsigned short* __restrict__ src16,
                                              const float* __restrict__ bias,
                                              float* __restrict__ outp, int n) {
    constexpr int G = 6;
    int t = blockIdx.x * blockDim.x + threadIdx.x;
    if (t >= n * G) return;
    const int node = t / G;
    const int g    = t % G;

    const us8* h8 = reinterpret_cast<const us8*>(h);

    float accA[8], accB[8];
    {
        us8 hv = h8[(size_t)node * G + g];
#pragma unroll
        for (int j = 0; j < 8; ++j) { accA[j] = bf2f(hv[j]); accB[j] = 0.f; }
    }

    const int beg = row_ptr[node];
    const int end = row_ptr[node + 1];
    int k = beg;
    int kA = min((beg + 7) & ~7, end);
    for (; k < kA; ++k) {
        us8 vv = h8[(size_t)src16[k] * G + g];
#pragma unroll
        for (int j = 0; j < 8; ++j) accA[j] += bf2f(vv[j]);
    }
    for (; k + 8 <= end; k += 8) {
        us8 si = *reinterpret_cast<const us8*>(src16 + k);
        us8 v0 = h8[(size_t)si[0] * G + g];
        us8 v1 = h8[(size_t)si[1] * G + g];
        us8 v2 = h8[(size_t)si[2] * G + g];
        us8 v3 = h8[(size_t)si[3] * G + g];
        us8 v4 = h8[(size_t)si[4] * G + g];
        us8 v5 = h8[(size_t)si[5] * G + g];
        us8 v6 = h8[(size_t)si[6] * G + g];
        us8 v7 = h8[(size_t)si[7] * G + g];
#pragma unroll
        for (int j = 0; j < 8; ++j) {
            accA[j] += (bf2f(v0[j]) + bf2f(v1[j])) + (bf2f(v4[j]) + bf2f(v5[j]));
            accB[j] += (bf2f(v2[j]) + bf2f(v3[j])) + (bf2f(v6[j]) + bf2f(v7[j]));
        }
    }
    for (; k < end; ++k) {
        us8 vv = h8[(size_t)src16[k] * G + g];
#pragma unroll
        for (int j = 0; j < 8; ++j) accB[j] += bf2f(vv[j]);
    }

    const float di = dinv[node];
    const float4* b4 = reinterpret_cast<const float4*>(bias);
    float4 b0 = b4[g * 2], b1 = b4[g * 2 + 1];
    float r[8];
#pragma unroll
    for (int j = 0; j < 8; ++j) r[j] = di * (accA[j] + accB[j]);
    r[0] += b0.x; r[1] += b0.y; r[2] += b0.z; r[3] += b0.w;
    r[4] += b1.x; r[5] += b1.y; r[6] += b1.z; r[7] += b1.w;
    float4* o4 = reinterpret_cast<float4*>(outp + (size_t)node * DO + g * 8);
    o4[0] = float4{r[0], r[1], r[2], r[3]};
    o4[1] = float4{r[4], r[5], r[6], r[7]};
}

// ---------------- launch ----------------

extern "C" void kernel_launch(void* const* d_in, const int* in_sizes, int n_in,
                              void* d_out, int out_size, void* d_ws, size_t ws_size,
                              hipStream_t stream) {
    const float* x   = (const float*)d_in[0];
    const int*   ei  = (const int*)d_in[1];   // [2][NE] int32
    const float* W1  = (const float*)d_in[2];
    const float* b1  = (const float*)d_in[3];
    const float* W2  = (const float*)d_in[4];
    const float* b2  = (const float*)d_in[5];
    float*       out = (float*)d_out;

    const int* srcv = ei;
    const int* dstv = ei + NE;

    // workspace layout (16B-aligned blocks)
    char* p = (char*)d_ws;
    float*          dinv  = (float*)p;           p += (size_t)NN * 4;
    unsigned short* h1    = (unsigned short*)p;  p += (size_t)NN * DH * 2;   // unscaled
    unsigned short* h2    = (unsigned short*)p;  p += (size_t)NN * DO * 2;   // pre-scaled
    int*      row_ptr     = (int*)p;             p += (size_t)(NN + 16) * 4;
    unsigned short* src16 = (unsigned short*)p;  p += (size_t)NE * 2;
    unsigned* epack       = (unsigned*)p;        p += (size_t)NE * 4;
    unsigned* ebuf        = (unsigned*)p;        p += (size_t)NE * 4;
    int*      Cm          = (int*)p;             p += (size_t)NBK * NCHUNK * 4;
    int*      totals      = (int*)p;             p += (size_t)NBK * 4;
    int*      bk_ptr      = (int*)p;             p += (size_t)(NBK + 1) * 4;

    const int B = 256;

    k_hist<<<NCHUNK, B, 0, stream>>>(dstv, Cm, NE);
    k_rowscan<<<(NBK + 3) / 4, B, 0, stream>>>(Cm, totals, row_ptr);
    k_scatter_gemm1<<<NCHUNK + NG1, B, 0, stream>>>(
        srcv, dstv, Cm, totals, bk_ptr, ebuf, NE, x, W1, h1, NN);
    k_bsort<<<NBK, B, 0, stream>>>(ebuf, bk_ptr, row_ptr, dinv, src16, NN);
    k_pack<<<(NE / 2 + B - 1) / B, B, 0, stream>>>(src16, dinv, epack, NE);

    // layer 1 agg + layer 2 gemm fused
    k_agg1_gemm2<<<NB2, 512, 0, stream>>>(h1, dinv, row_ptr, epack, b1, W2, h2, NN);

    // layer 2 agg -> f32 out
    {
        int total = NN * 6;
        k_agg2<<<(total + B - 1) / B, B, 0, stream>>>(
            h2, dinv, row_ptr, src16, b2, out, NN);
    }
}